// Round 8
// baseline (136.006 us; speedup 1.0000x reference)
//
#include <hip/hip_runtime.h>
#include <hip/hip_bf16.h>
#include <stdint.h>

// ===================================================================
// PriorLayer online BP scan, round 10. s_t = norm(diag(p_t) T s_{t-1}).
// R9 = R7 = 52.4us to 0.5%: barrier-group size, LDS reads/epoch, MFMA
// count, conflicts, shuffles ALL don't move per-epoch (~5700cyc).
// Cross-round accounting: per-CU HBM rate pinned 8.6-9.7 GB/s/CU in
// every variant incl. R3's 2-block (perfectly serialized); bottom-up
// chain model ~800cyc vs 5700 observed. Remaining invariant shared by
// all rounds AND by two blocks on one CU: FULLY-UNROLLED epoch code
// (~40-55KB) exceeding the 32KB per-CU L1I => every epoch streams
// instructions from L2; in-order waves can't hide I-fetch; grows with
// body size (R5) and with split unrolled loops (R6-R9 regression);
// R8's 20k cyc/epoch fits too.
// R10 = R9 VERBATIM (same math/layouts/schedule) with epoch loops
// FORCED ROLLED (unroll(disable)); cur/nxt stay compile-time via the
// even/odd pair inside the loop body. Hot code ~8KB -> L1I-resident.
// ===================================================================

#define DIM   256
#define SEQ   65536
#define G     16                    // chunks per block (MFMA cols)
#define CLEN  16                    // outputs per chunk
#define NBLK  (SEQ / (G * CLEN))    // 256 blocks -> 1 per CU
#define BURN  6
#define STEPS (BURN + CLEN)         // 22 (even — pairing relies on it)
#define NW    4
#define TPB   (NW * 64)             // 256
#define PGP   17                    // pZL padded row (f32x2)

typedef short bf16x8 __attribute__((ext_vector_type(8)));
typedef float f32x4  __attribute__((ext_vector_type(4)));
typedef float f32x2  __attribute__((ext_vector_type(2)));

static __device__ __forceinline__ unsigned short f2bf(float x) {
  __hip_bfloat16 h = __float2bfloat16(x);
  return *reinterpret_cast<unsigned short*>(&h);
}

// LDS-only barrier: do NOT drain vmcnt (global stores / prefetch loads
// stay in flight). lgkmcnt(0) orders all ds ops.
static __device__ __forceinline__ void lds_barrier() {
  asm volatile("s_waitcnt lgkmcnt(0)" ::: "memory");
  __builtin_amdgcn_s_barrier();
}

__global__ __launch_bounds__(TPB, 1)
void prior_scan_kernel(const float* __restrict__ probs,
                       const float* __restrict__ tp,
                       float* __restrict__ out) {
  // SB: double-buffered state, fragment-major SB[buf][kb][lane][j]
  //     (reads linear/conflict-free; writes scatter ~linear).
  // pZL: parity-buffered lane partials [par][n][g=w*4+quad].
  __shared__ __attribute__((aligned(16))) short SB[2][8][64][8];
  __shared__ __attribute__((aligned(16))) f32x2 pZL[2][G][PGP];

  const int tid  = threadIdx.x;
  const int w    = tid >> 6;
  const int lane = tid & 63;
  const int n    = lane & 15;       // chunk within block = MFMA col
  const int quad = lane >> 4;
  const int g    = blockIdx.x * G + n;   // global chunk id (per lane)

  // ---- T rows w*64..w*64+63 into A-fragments (128 VGPR, resident)
  //      A[rt][kb]: m=lane&15 -> row w*64+rt*16+m; k=quad*8+j
  bf16x8 A[4][8];
#pragma unroll
  for (int rt = 0; rt < 4; rt++) {
    const int row = w * 64 + rt * 16 + n;
#pragma unroll
    for (int kb = 0; kb < 8; kb++) {
      const float* p = tp + row * DIM + kb * 32 + quad * 8;
      f32x4 f0 = *reinterpret_cast<const f32x4*>(p);
      f32x4 f1 = *reinterpret_cast<const f32x4*>(p + 4);
      bf16x8 a;
#pragma unroll
      for (int j = 0; j < 4; j++) {
        a[j]     = (short)f2bf(f0[j]);
        a[4 + j] = (short)f2bf(f1[j]);
      }
      A[rt][kb] = a;
    }
  }

  // ---- init state buf 0 = uniform 1/256 (bf16-exact; scale-invariant)
  {
    ushort4 u; u.x = u.y = u.z = u.w = (unsigned short)0x3B80;
    ushort4* dst = reinterpret_cast<ushort4*>(&SB[0][0][0][0]) + tid * 4;
    dst[0] = u; dst[1] = u; dst[2] = u; dst[3] = u;   // 4096 shorts total
  }

  // ---- observation fragment loader (lane-owned, direct from global)
  auto loadp = [&](int s, int rt, bool clamp) -> f32x4 {
    int t = g * CLEN - BURN + s;
    if (clamp && t < 0) t = 0;      // value unused when t<0
    return *reinterpret_cast<const f32x4*>(
        probs + (size_t)t * DIM + w * 64 + rt * 16 + quad * 4);
  };

  // 2-deep register prefetch ring
  f32x4 pf[2][4];
#pragma unroll
  for (int rt = 0; rt < 4; rt++) {
    pf[0][rt] = loadp(0, rt, true);
    pf[1][rt] = loadp(1, rt, true);
  }

  __syncthreads();                  // A/pf are private; orders SB init

  float qp[4][4];                   // q of previous epoch (deferred norm)

  // --- full 256-dim matvec, this wave's 64 rows: q = (T @ u) .* p
  auto matvec = [&](int cur, float (&q)[4][4]) {
    bf16x8 B[8];
#pragma unroll
    for (int kb = 0; kb < 8; kb++)  // linear conflict-free b128
      B[kb] = *reinterpret_cast<const bf16x8*>(&SB[cur][kb][lane][0]);
    f32x4 aE[4], aO[4];
#pragma unroll
    for (int rt = 0; rt < 4; rt++) {
      aE[rt] = f32x4{0.f, 0.f, 0.f, 0.f};
      aO[rt] = f32x4{0.f, 0.f, 0.f, 0.f};
    }
#pragma unroll
    for (int kb = 0; kb < 8; kb += 2) {
#pragma unroll
      for (int rt = 0; rt < 4; rt++) {
        aE[rt] = __builtin_amdgcn_mfma_f32_16x16x32_bf16(A[rt][kb],     B[kb],     aE[rt], 0, 0, 0);
        aO[rt] = __builtin_amdgcn_mfma_f32_16x16x32_bf16(A[rt][kb + 1], B[kb + 1], aO[rt], 0, 0, 0);
      }
    }
#pragma unroll
    for (int rt = 0; rt < 4; rt++)
#pragma unroll
      for (int v = 0; v < 4; v++)   // C/D: row=rt*16+quad*4+v, col=n
        q[rt][v] = (aE[rt][v] + aO[rt][v]) * pf[cur][rt][v];
  };

  // write map: r=w*64+rt*16+quad*4+v -> kb=w*2+(rt>>1),
  //            qd=(rt&1)*2+(quad>>1), j=(quad&1)*4+v  (R7-verified)
  auto write_state = [&](int nxt, const float (&q)[4][4]) {
#pragma unroll
    for (int rt = 0; rt < 4; rt++) {
      ushort4 sp;
      sp.x = f2bf(q[rt][0] * 0.015625f);
      sp.y = f2bf(q[rt][1] * 0.015625f);
      sp.z = f2bf(q[rt][2] * 0.015625f);
      sp.w = f2bf(q[rt][3] * 0.015625f);
      *reinterpret_cast<ushort4*>(
          &SB[nxt][w * 2 + (rt >> 1)][((rt & 1) * 2 + (quad >> 1)) * 16 + n]
             [(quad & 1) * 4]) = sp;
    }
  };

  // --- deferred finalize of epoch e1 (partials in pZL[pbuf])
  auto finalize = [&](int pbuf, int e1) {
    float Z = 0.f, L = 0.f;
#pragma unroll
    for (int j = 0; j < 8; j++) {   // 16 f32x2 partials for chunk n
      f32x4 r = *reinterpret_cast<const f32x4*>(&pZL[pbuf][n][j * 2]);
      Z += r[0] + r[2];
      L += r[1] + r[3];
    }
    const float zi = __builtin_amdgcn_rcpf(Z);
    const int t1 = g * CLEN + (e1 - BURN);
#pragma unroll
    for (int rt = 0; rt < 4; rt++) {
      f32x4 o;
#pragma unroll
      for (int v = 0; v < 4; v++) o[v] = qp[rt][v] * zi;
      *reinterpret_cast<f32x4*>(
          out + (size_t)t1 * DIM + w * 64 + rt * 16 + quad * 4) = o;
    }
    if (tid < 16)                   // n == tid for these lanes
      out[(size_t)SEQ * DIM + t1] = __logf(Z) - L * zi;
  };

  // --- burn epoch: NO partials, NO finalize, NO qp carry
  auto burn_body = [&](int e, int cur, int nxt) {
    float q[4][4];
    matvec(cur, q);
#pragma unroll
    for (int rt = 0; rt < 4; rt++)
      pf[cur][rt] = loadp(e + 2, rt, true);   // e+2 <= BURN+1 < STEPS
    const int t = g * CLEN - BURN + e;
    if (t < 0) {                    // pre-start: hold uniform state
      ushort4 sp;
      sp.x = sp.y = sp.z = sp.w = (unsigned short)0x3B80;
#pragma unroll
      for (int rt = 0; rt < 4; rt++)
        *reinterpret_cast<ushort4*>(
            &SB[nxt][w * 2 + (rt >> 1)][((rt & 1) * 2 + (quad >> 1)) * 16 + n]
               [(quad & 1) * 4]) = sp;
    } else {
      write_state(nxt, q);
    }
    lds_barrier();
  };

  // --- output epoch: lane-private partials + deferred finalize of e-1
  auto main_body = [&](int e, int cur, int nxt) {
    float q[4][4];
    matvec(cur, q);
    int ps = e + 2; if (ps > STEPS - 1) ps = STEPS - 1;
#pragma unroll
    for (int rt = 0; rt < 4; rt++)
      pf[cur][rt] = loadp(ps, rt, false);     // t >= 0 for all mains
    write_state(nxt, q);

    float sz = 0.f, sl = 0.f;       // lane-private over 16 rows
#pragma unroll
    for (int rt = 0; rt < 4; rt++)
#pragma unroll
      for (int v = 0; v < 4; v++) {
        float qq = q[rt][v];
        sz += qq;
        sl += qq * __logf(qq + 1e-30f);
      }
    pZL[cur][n][w * 4 + quad] = f32x2{sz, sl};

    if (e > BURN) finalize(nxt, e - 1);       // nxt == (e-1)&1

#pragma unroll
    for (int rt = 0; rt < 4; rt++)
#pragma unroll
      for (int v = 0; v < 4; v++) qp[rt][v] = q[rt][v];
    lds_barrier();
  };

  // ROLLED epoch loops: hot code = one even/odd pair per loop (~8KB),
  // L1I-resident. cur/nxt remain compile-time inside the pair.
#pragma clang loop unroll(disable)
  for (int e = 0; e < BURN; e += 2) {         // BURN even
    burn_body(e, 0, 1);
    burn_body(e + 1, 1, 0);
  }
#pragma clang loop unroll(disable)
  for (int e = BURN; e < STEPS; e += 2) {     // STEPS even, BURN even
    main_body(e, 0, 1);
    main_body(e + 1, 1, 0);
  }

  // --- tail: finalize epoch STEPS-1 (partials in pZL[(STEPS-1)&1])
  finalize((STEPS - 1) & 1, STEPS - 1);
}

extern "C" void kernel_launch(void* const* d_in, const int* in_sizes, int n_in,
                              void* d_out, int out_size, void* d_ws, size_t ws_size,
                              hipStream_t stream) {
  const float* probs = (const float*)d_in[0];   // (65536, 256)
  const float* tp    = (const float*)d_in[1];   // (256, 256)
  float* out         = (float*)d_out;           // 65536*256 probs + 65536 H

  hipLaunchKernelGGL(prior_scan_kernel, dim3(NBLK), dim3(TPB), 0, stream,
                     probs, tp, out);
}